// Round 9
// baseline (208.817 us; speedup 1.0000x reference)
//
#include <hip/hip_runtime.h>
#include <hip/hip_bf16.h>

#define EPSF 1e-14f
#define RHOF 8.0f

typedef __attribute__((ext_vector_type(4))) float f32x4;
typedef __attribute__((ext_vector_type(2))) unsigned long long u64x2;

#define AS_GLOBAL __attribute__((address_space(1)))
#define AS_LDS    __attribute__((address_space(3)))

// fp8 packed layout, BK=64 (unchanged from round 6/8; conflicts measured 0).
// Tile = 128 rows x 64 cols fp8 = 8 KB = 512 units of 16 B. Row r = 8
// granules of 8 B; granule g stored at slot g ^ m(r), m(r) = (r>>1)&7.
// Fragment read (sub-step s, quad qd): byte r*64 + (s^x2)*32 + xq*8,
// x2=(lo>>3)&1, xq=qd^((lo>>1)&3). m(r) depends only on r mod 16, so any
// 64-row half of a tile uses identical per-lane offsets.

__global__ __launch_bounds__(256) void prep_fp8(
    const float* __restrict__ im,  const float* __restrict__ tt,
    const float* __restrict__ rim, const float* __restrict__ rtt,
    unsigned char* __restrict__ bIm,  unsigned char* __restrict__ bTt,
    unsigned char* __restrict__ bRim, unsigned char* __restrict__ bRtt,
    float* __restrict__ S_im, float* __restrict__ S_tt,
    float* __restrict__ diag, float* __restrict__ red,
    int D, int spm /* 8-row slabs per matrix */)
{
    __shared__ unsigned char L[8 * 1024];   // 8 rows x D fp8 (D<=1024)
    const int b = blockIdx.x;
    const int tid = threadIdx.x;
    const int nConv = 4 * spm;
    if (b < nConv) {
        int mIdx = b / spm;
        int slab = b - mIdx * spm;
        const float* src = (mIdx == 0) ? rim : (mIdx == 1) ? tt
                          : (mIdx == 2) ? rtt : im;
        unsigned char* dst = (mIdx == 0) ? bRim : (mIdx == 1) ? bTt
                            : (mIdx == 2) ? bRtt : bIm;
        const float* srow = src + (size_t)slab * 8 * D;
        const int n4 = (8 * D) >> 2;
        for (int idx = tid; idx < n4; idx += 256) {
            float4 v = *(const float4*)(srow + idx * 4);
            int pk = __builtin_amdgcn_cvt_pk_fp8_f32(v.x, v.y, 0, false);
            pk     = __builtin_amdgcn_cvt_pk_fp8_f32(v.z, v.w, pk, true);
            *(int*)&L[idx * 4] = pk;
        }
        __syncthreads();
        const int kTiles = D >> 6;
        const int rb = (slab * 8) >> 7;
        const int r0loc = (slab * 8) & 127;
        for (int g = tid; g < (D >> 1); g += 256) {
            int kb  = g >> 5;
            int rem = g & 31;
            int rl  = rem >> 2;
            int h   = rem & 3;
            int r   = slab * 8 + rl;
            int m   = (r >> 1) & 7;
            int g0  = (2 * h) ^ m;
            const unsigned char* lb = &L[rl * D + kb * 64];
            u64x2 o;
            o.x = *(const unsigned long long*)(lb + g0 * 8);
            o.y = *(const unsigned long long*)(lb + (g0 ^ 1) * 8);
            char* outp = (char*)dst
                       + ((size_t)(rb * kTiles + kb) * 512
                          + (size_t)(r0loc + rl) * 4 + h) * 16;
            *(u64x2*)outp = o;
        }
    } else {
        int db = b - nConv;
        if (db == 0 && tid < 8) red[tid] = 0.f;
        if (tid < 4) { S_im[db * 4 + tid] = 0.f; S_tt[db * 4 + tid] = 0.f; }
        int row  = db * 4 + (tid >> 6);
        int lane = tid & 63;
        const float* a = rim + (size_t)row * D;
        const float* c = rtt + (size_t)row * D;
        float s = 0.f;
        for (int k = lane * 4; k < D; k += 256) {
            float4 av = *(const float4*)(a + k);
            float4 cv = *(const float4*)(c + k);
            s += av.x * cv.x + av.y * cv.y + av.z * cv.z + av.w * cv.w;
        }
        #pragma unroll
        for (int m2 = 1; m2 < 64; m2 <<= 1) s += __shfl_xor(s, m2, 64);
        if (lane == 0) diag[row] = s;
    }
}

// fp8 GEMM, barrier-free: each wave owns a private 64x64 tile and a private
// 8 KB LDS slice. No __syncthreads in the K-loop — wave-level s_waitcnt only;
// latency hiding via TLP across ~16-20 independent waves/CU.
__global__ __launch_bounds__(256) void gemm_expsum(
    const unsigned char* __restrict__ A0, const unsigned char* __restrict__ B0,
    float* __restrict__ S0,
    const unsigned char* __restrict__ A1, const unsigned char* __restrict__ B1,
    float* __restrict__ S1,
    const float* __restrict__ logit_scale, const int* __restrict__ offset,
    int Bn, int D)
{
    const int z = blockIdx.z;
    const unsigned char* A = z ? A1 : A0;
    const unsigned char* B = z ? B1 : B0;
    float* S = z ? S1 : S0;

    __shared__ unsigned char As[4][4096];   // per-wave A half-tile (64x64)
    __shared__ unsigned char Bs[4][4096];   // per-wave B half-tile

    const int tid  = threadIdx.x;
    const int wave = tid >> 6;
    const int lane = tid & 63;
    const int lo   = lane & 15;
    const int qd   = lane >> 4;
    const int m0   = (wave >> 1) * 64;      // wave's row half within 128-tile
    const int n0   = (wave & 1) * 64;       // wave's col half
    const int x2   = (lo >> 3) & 1;
    const int xq   = qd ^ ((lo >> 1) & 3);
    const int off0 = x2 * 32 + xq * 8;
    const int off1 = (1 - x2) * 32 + xq * 8;

    const int kTiles = D >> 6;
    // wave's 64-row half = contiguous 4 KB run inside the packed 8 KB tile
    const unsigned char* Ahalf = A + (size_t)blockIdx.y * kTiles * 8192 + m0 * 64;
    const unsigned char* Bhalf = B + (size_t)blockIdx.x * kTiles * 8192 + n0 * 64;

    f32x4 acc[4][4];
    #pragma unroll
    for (int i = 0; i < 4; ++i)
        #pragma unroll
        for (int j = 0; j < 4; ++j)
            acc[i][j] = (f32x4){0.f, 0.f, 0.f, 0.f};

    for (int kb = 0; kb < kTiles; ++kb) {
        #pragma unroll
        for (int j = 0; j < 4; ++j) {
            int goff = (j * 64 + lane) * 16;           // 4 KB per half-tile
            __builtin_amdgcn_global_load_lds(
                (const AS_GLOBAL unsigned int*)(Ahalf + goff),
                (AS_LDS unsigned int*)&As[wave][j * 1024], 16, 0, 0);
            __builtin_amdgcn_global_load_lds(
                (const AS_GLOBAL unsigned int*)(Bhalf + goff),
                (AS_LDS unsigned int*)&Bs[wave][j * 1024], 16, 0, 0);
        }
        // no barrier: compiler inserts wave-level s_waitcnt vmcnt before the
        // dependent ds_reads; other waves keep the MFMA pipe busy meanwhile.

        long af0[4], af1[4], bq0[4], bq1[4];
        #pragma unroll
        for (int t = 0; t < 4; ++t) {
            int ra = (16 * t + lo) * 64;               // row within the half
            af0[t] = *(const long*)&As[wave][ra + off0];
            af1[t] = *(const long*)&As[wave][ra + off1];
            bq0[t] = *(const long*)&Bs[wave][ra + off0];
            bq1[t] = *(const long*)&Bs[wave][ra + off1];
        }
        #pragma unroll
        for (int ti = 0; ti < 4; ++ti)
            #pragma unroll
            for (int tj = 0; tj < 4; ++tj) {
                acc[ti][tj] = __builtin_amdgcn_mfma_f32_16x16x32_fp8_fp8(
                    af0[ti], bq0[tj], acc[ti][tj], 0, 0, 0);
                acc[ti][tj] = __builtin_amdgcn_mfma_f32_16x16x32_fp8_fp8(
                    af1[ti], bq1[tj], acc[ti][tj], 0, 0, 0);
            }

        Ahalf += 8192;
        Bhalf += 8192;
    }

    const float ls = logit_scale[0];
    const int offs = offset[0];
    const int rowBase = blockIdx.y * 128;
    const int colBase = blockIdx.x * 128;
    #pragma unroll
    for (int ti = 0; ti < 4; ++ti) {
        #pragma unroll
        for (int r = 0; r < 4; ++r) {
            int gi = rowBase + m0 + 16 * ti + 4 * qd + r;   // C/D row=quad*4+reg
            float rs = 0.f;
            #pragma unroll
            for (int tj = 0; tj < 4; ++tj) {
                int gj = colBase + n0 + 16 * tj + lo;        // C/D col=lane&15
                float e = __expf(ls * acc[ti][tj][r]);
                if (gj == gi + offs) e = 0.f;                // shifted diagonal
                rs += e;
            }
            #pragma unroll
            for (int m = 1; m < 16; m <<= 1) rs += __shfl_xor(rs, m, 64);
            if (lo == 0) atomicAdd(&S[gi], rs);
        }
    }
}

// 8-block reduction; last block (ticket) computes the scalar loss.
__global__ __launch_bounds__(256) void final_kernel(
    const float* __restrict__ S_im, const float* __restrict__ S_tt,
    const float* __restrict__ diag,
    const float* __restrict__ ru_im, const float* __restrict__ ru_tt,
    const float* __restrict__ l1_im, const float* __restrict__ l1_tt,
    const float* __restrict__ u_im,  const float* __restrict__ u_tt,
    const float* __restrict__ logit_scale, float* __restrict__ red,
    float* __restrict__ out, int Bn)
{
    const float ls = logit_scale[0];
    const float inv_rw = 1.0f / (float)(Bn - 1);
    const int gid = blockIdx.x * 256 + threadIdx.x;
    float pg = 0.f, lg = 0.f;
    for (int i = gid; i < Bn; i += 8 * 256) {
        float p1 = l1_im[i] / (u_im[i] + EPSF) + l1_tt[i] / (u_tt[i] + EPSF);
        float dd = expf(-ls * diag[i]);
        float p2 = dd * S_im[i] * inv_rw / (ru_im[i] + EPSF)
                 + dd * S_tt[i] * inv_rw / (ru_tt[i] + EPSF);
        pg += p1 + p2;
        lg += logf(u_im[i]) + logf(u_tt[i]);
    }
    __shared__ float sp[256], sl[256];
    sp[threadIdx.x] = pg; sl[threadIdx.x] = lg;
    __syncthreads();
    for (int s = 128; s > 0; s >>= 1) {
        if (threadIdx.x < s) { sp[threadIdx.x] += sp[threadIdx.x + s];
                               sl[threadIdx.x] += sl[threadIdx.x + s]; }
        __syncthreads();
    }
    if (threadIdx.x == 0) {
        atomicAdd(&red[0], sp[0]);
        atomicAdd(&red[1], sl[0]);
        __threadfence();
        int t = atomicAdd((int*)&red[2], 1);
        if (t == gridDim.x - 1) {
            float pgSum = atomicAdd(&red[0], 0.f);
            float lgSum = atomicAdd(&red[1], 0.f);
            float loss = ((pgSum / (float)Bn) * 0.5f) / ls
                       + RHOF / ls
                       + (lgSum / (float)Bn) * 0.5f / ls;
            out[0] = loss;
        }
    }
}

extern "C" void kernel_launch(void* const* d_in, const int* in_sizes, int n_in,
                              void* d_out, int out_size, void* d_ws, size_t ws_size,
                              hipStream_t stream) {
    const float* im    = (const float*)d_in[0];
    const float* tt    = (const float*)d_in[1];
    const float* rim   = (const float*)d_in[2];
    const float* rtt   = (const float*)d_in[3];
    const float* ru_im = (const float*)d_in[4];
    const float* ru_tt = (const float*)d_in[5];
    const float* l1_im = (const float*)d_in[6];
    const float* l1_tt = (const float*)d_in[7];
    const float* u_im  = (const float*)d_in[8];
    const float* u_tt  = (const float*)d_in[9];
    const float* lsc   = (const float*)d_in[10];
    const int*   offs  = (const int*)d_in[11];

    const int Bn = in_sizes[4];          // 4096
    const int D  = in_sizes[0] / Bn;     // 1024
    const int spm = Bn / 8;              // 8-row slabs per matrix

    char* base = (char*)d_ws;
    float* S_im = (float*)base;
    float* S_tt = S_im + Bn;
    float* diag = S_tt + Bn;
    float* red  = diag + Bn;             // [0]=pg, [1]=lg, [2]=ticket
    const size_t headBytes = (((size_t)(3 * Bn + 8) * sizeof(float)) + 255) & ~(size_t)255;
    const size_t matBytes  = (size_t)Bn * D;          // fp8: 1 B/elem
    unsigned char* buf0 = (unsigned char*)(base + headBytes);
    unsigned char* bRim = buf0;
    unsigned char* bTt  = buf0 + matBytes;
    unsigned char* bRtt = buf0 + 2 * matBytes;
    unsigned char* bIm  = buf0 + 3 * matBytes;

    prep_fp8<<<4 * spm + Bn / 4, 256, 0, stream>>>(
        im, tt, rim, rtt, bIm, bTt, bRim, bRtt, S_im, S_tt, diag, red, D, spm);

    dim3 ggrid(Bn / 128, Bn / 128, 2);
    gemm_expsum<<<ggrid, 256, 0, stream>>>(bRim, bTt, S_im, bRtt, bIm, S_tt,
                                           lsc, offs, Bn, D);

    final_kernel<<<8, 256, 0, stream>>>(S_im, S_tt, diag, ru_im, ru_tt,
                                        l1_im, l1_tt, u_im, u_tt, lsc,
                                        red, (float*)d_out, Bn);
}

// Round 10
// 186.387 us; speedup vs baseline: 1.1203x; 1.1203x over previous
//
#include <hip/hip_runtime.h>
#include <hip/hip_bf16.h>

#define EPSF 1e-14f
#define RHOF 8.0f

typedef __attribute__((ext_vector_type(4))) float f32x4;
typedef __attribute__((ext_vector_type(8))) int   i32x8;
typedef __attribute__((ext_vector_type(2))) unsigned long long u64x2;

#define AS_GLOBAL __attribute__((address_space(1)))
#define AS_LDS    __attribute__((address_space(3)))

// fp8 packed layout, BK=128 (for mfma_scale 16x16x128). Tile = 128 rows x
// 128 cols fp8 = 16 KB = 1024 units of 16 B. Row r = 8 units; content unit
// u stored at slot u ^ (r&7). Fragment (quad qd) needs k-block qd*32..+31 =
// content units {2qd, 2qd+1} -> slots s0=(2qd)^(lo&7), s0^1: two
// ds_read_b128. Per 16-lane phase s0 covers 8 slots twice -> 32 banks
// 2-way (free, m136). global_load_lds deposit order == packed order.

__global__ __launch_bounds__(256) void prep_fp8(
    const float* __restrict__ im,  const float* __restrict__ tt,
    const float* __restrict__ rim, const float* __restrict__ rtt,
    unsigned char* __restrict__ bIm,  unsigned char* __restrict__ bTt,
    unsigned char* __restrict__ bRim, unsigned char* __restrict__ bRtt,
    float* __restrict__ S_im, float* __restrict__ S_tt,
    float* __restrict__ diag, float* __restrict__ red,
    int D, int spm /* 8-row slabs per matrix */)
{
    __shared__ unsigned char L[8 * 1024];   // 8 rows x D fp8 (D<=1024)
    const int b = blockIdx.x;
    const int tid = threadIdx.x;
    const int nConv = 4 * spm;
    if (b < nConv) {
        int mIdx = b / spm;
        int slab = b - mIdx * spm;
        const float* src = (mIdx == 0) ? rim : (mIdx == 1) ? tt
                          : (mIdx == 2) ? rtt : im;
        unsigned char* dst = (mIdx == 0) ? bRim : (mIdx == 1) ? bTt
                            : (mIdx == 2) ? bRtt : bIm;
        const float* srow = src + (size_t)slab * 8 * D;
        const int n4 = (8 * D) >> 2;
        for (int idx = tid; idx < n4; idx += 256) {
            float4 v = *(const float4*)(srow + idx * 4);
            int pk = __builtin_amdgcn_cvt_pk_fp8_f32(v.x, v.y, 0, false);
            pk     = __builtin_amdgcn_cvt_pk_fp8_f32(v.z, v.w, pk, true);
            *(int*)&L[idx * 4] = pk;
        }
        __syncthreads();
        const int kTiles = D >> 7;               // 128-wide k tiles
        const int rb = (slab * 8) >> 7;
        const int r0loc = (slab * 8) & 127;
        for (int g = tid; g < (D >> 1); g += 256) {  // units per slab = D/2
            int kb  = g >> 6;                    // 64 units per (slab,kb)
            int rem = g & 63;
            int rl  = rem >> 3;
            int p   = rem & 7;                   // slot position
            int r   = slab * 8 + rl;
            int c   = p ^ (r & 7);               // content unit at slot p
            const unsigned char* lb = &L[rl * D + kb * 128 + c * 16];
            u64x2 o = *(const u64x2*)lb;
            char* outp = (char*)dst
                       + ((size_t)(rb * kTiles + kb) * 1024
                          + (size_t)(r0loc + rl) * 8 + p) * 16;
            *(u64x2*)outp = o;
        }
    } else {
        int db = b - nConv;
        if (db == 0 && tid < 8) red[tid] = 0.f;
        if (tid < 4) { S_im[db * 4 + tid] = 0.f; S_tt[db * 4 + tid] = 0.f; }
        int row  = db * 4 + (tid >> 6);
        int lane = tid & 63;
        const float* a = rim + (size_t)row * D;
        const float* c = rtt + (size_t)row * D;
        float s = 0.f;
        for (int k = lane * 4; k < D; k += 256) {
            float4 av = *(const float4*)(a + k);
            float4 cv = *(const float4*)(c + k);
            s += av.x * cv.x + av.y * cv.y + av.z * cv.z + av.w * cv.w;
        }
        #pragma unroll
        for (int m2 = 1; m2 < 64; m2 <<= 1) s += __shfl_xor(s, m2, 64);
        if (lane == 0) diag[row] = s;
    }
}

// MX-scaled fp8 GEMM (BK=128, K=128 per MFMA, scales=1.0) with round-8's
// single-barrier async double-buffer. + exp + masked row-sum epilogue.
__global__ __launch_bounds__(256) void gemm_expsum(
    const unsigned char* __restrict__ A0, const unsigned char* __restrict__ B0,
    float* __restrict__ S0,
    const unsigned char* __restrict__ A1, const unsigned char* __restrict__ B1,
    float* __restrict__ S1,
    const float* __restrict__ logit_scale, const int* __restrict__ offset,
    int Bn, int D)
{
    const int z = blockIdx.z;
    const unsigned char* A = z ? A1 : A0;
    const unsigned char* B = z ? B1 : B0;
    float* S = z ? S1 : S0;

    __shared__ unsigned char As[2][16384];   // 128x128 fp8, unit-packed, dbuf
    __shared__ unsigned char Bs[2][16384];

    const int tid  = threadIdx.x;
    const int wave = tid >> 6;
    const int lane = tid & 63;
    const int lo   = lane & 15;
    const int qd   = lane >> 4;
    const int m0   = (wave >> 1) * 64;
    const int n0   = (wave & 1) * 64;
    const int s0   = (2 * qd) ^ (lo & 7);    // first 16-B slot of k-block
    const int offA = s0 * 16;
    const int offB = (s0 ^ 1) * 16;

    const int kTiles = D >> 7;
    const unsigned char* Atile = A + (size_t)blockIdx.y * kTiles * 16384;
    const unsigned char* Btile = B + (size_t)blockIdx.x * kTiles * 16384;

    auto stage = [&](int buf, const unsigned char* At, const unsigned char* Bt) {
        #pragma unroll
        for (int j = 0; j < 4; ++j) {
            int goff = (j * 256 + tid) * 16;          // 16 KB per matrix
            int loff = j * 4096 + wave * 1024;        // wave-uniform base
            __builtin_amdgcn_global_load_lds(
                (const AS_GLOBAL unsigned int*)(At + goff),
                (AS_LDS unsigned int*)&As[buf][loff], 16, 0, 0);
            __builtin_amdgcn_global_load_lds(
                (const AS_GLOBAL unsigned int*)(Bt + goff),
                (AS_LDS unsigned int*)&Bs[buf][loff], 16, 0, 0);
        }
    };

    f32x4 acc[4][4];
    #pragma unroll
    for (int i = 0; i < 4; ++i)
        #pragma unroll
        for (int j = 0; j < 4; ++j)
            acc[i][j] = (f32x4){0.f, 0.f, 0.f, 0.f};

    stage(0, Atile, Btile);
    __syncthreads();          // drain prologue DMA

    for (int kb = 0; kb < kTiles; ++kb) {
        const int cur = kb & 1;
        if (kb + 1 < kTiles)
            stage(1 - cur, Atile + 16384, Btile + 16384);   // prefetch kb+1

        i32x8 bq[4];
        #pragma unroll
        for (int t = 0; t < 4; ++t) {
            int rn = (n0 + 16 * t + lo) * 128;
            union { int4 h[2]; i32x8 v; } u;
            u.h[0] = *(const int4*)&Bs[cur][rn + offA];
            u.h[1] = *(const int4*)&Bs[cur][rn + offB];
            bq[t] = u.v;
        }
        #pragma unroll
        for (int ti = 0; ti < 4; ++ti) {
            int ra = (m0 + 16 * ti + lo) * 128;
            union { int4 h[2]; i32x8 v; } u;
            u.h[0] = *(const int4*)&As[cur][ra + offA];
            u.h[1] = *(const int4*)&As[cur][ra + offB];
            i32x8 af = u.v;
            #pragma unroll
            for (int tj = 0; tj < 4; ++tj)
                acc[ti][tj] = __builtin_amdgcn_mfma_scale_f32_16x16x128_f8f6f4(
                    af, bq[tj], acc[ti][tj],
                    0, 0,          // cbsz=fp8(e4m3), blgp=fp8(e4m3)
                    0, 127,        // scale A: opsel 0, E8M0 127 = x1.0
                    0, 127);       // scale B
        }
        __syncthreads();   // everyone done with buf[cur]; drains kb+1 DMA
                           // that has had the whole compute phase in flight

        Atile += 16384;
        Btile += 16384;
    }

    const float ls = logit_scale[0];
    const int offs = offset[0];
    const int rowBase = blockIdx.y * 128;
    const int colBase = blockIdx.x * 128;
    #pragma unroll
    for (int ti = 0; ti < 4; ++ti) {
        #pragma unroll
        for (int r = 0; r < 4; ++r) {
            int gi = rowBase + m0 + 16 * ti + 4 * qd + r;   // C/D row=quad*4+reg
            float rs = 0.f;
            #pragma unroll
            for (int tj = 0; tj < 4; ++tj) {
                int gj = colBase + n0 + 16 * tj + lo;        // C/D col=lane&15
                float e = __expf(ls * acc[ti][tj][r]);
                if (gj == gi + offs) e = 0.f;                // shifted diagonal
                rs += e;
            }
            #pragma unroll
            for (int m = 1; m < 16; m <<= 1) rs += __shfl_xor(rs, m, 64);
            if (lo == 0) atomicAdd(&S[gi], rs);
        }
    }
}

// 8-block reduction; last block (ticket) computes the scalar loss.
__global__ __launch_bounds__(256) void final_kernel(
    const float* __restrict__ S_im, const float* __restrict__ S_tt,
    const float* __restrict__ diag,
    const float* __restrict__ ru_im, const float* __restrict__ ru_tt,
    const float* __restrict__ l1_im, const float* __restrict__ l1_tt,
    const float* __restrict__ u_im,  const float* __restrict__ u_tt,
    const float* __restrict__ logit_scale, float* __restrict__ red,
    float* __restrict__ out, int Bn)
{
    const float ls = logit_scale[0];
    const float inv_rw = 1.0f / (float)(Bn - 1);
    const int gid = blockIdx.x * 256 + threadIdx.x;
    float pg = 0.f, lg = 0.f;
    for (int i = gid; i < Bn; i += 8 * 256) {
        float p1 = l1_im[i] / (u_im[i] + EPSF) + l1_tt[i] / (u_tt[i] + EPSF);
        float dd = expf(-ls * diag[i]);
        float p2 = dd * S_im[i] * inv_rw / (ru_im[i] + EPSF)
                 + dd * S_tt[i] * inv_rw / (ru_tt[i] + EPSF);
        pg += p1 + p2;
        lg += logf(u_im[i]) + logf(u_tt[i]);
    }
    __shared__ float sp[256], sl[256];
    sp[threadIdx.x] = pg; sl[threadIdx.x] = lg;
    __syncthreads();
    for (int s = 128; s > 0; s >>= 1) {
        if (threadIdx.x < s) { sp[threadIdx.x] += sp[threadIdx.x + s];
                               sl[threadIdx.x] += sl[threadIdx.x + s]; }
        __syncthreads();
    }
    if (threadIdx.x == 0) {
        atomicAdd(&red[0], sp[0]);
        atomicAdd(&red[1], sl[0]);
        __threadfence();
        int t = atomicAdd((int*)&red[2], 1);
        if (t == gridDim.x - 1) {
            float pgSum = atomicAdd(&red[0], 0.f);
            float lgSum = atomicAdd(&red[1], 0.f);
            float loss = ((pgSum / (float)Bn) * 0.5f) / ls
                       + RHOF / ls
                       + (lgSum / (float)Bn) * 0.5f / ls;
            out[0] = loss;
        }
    }
}

extern "C" void kernel_launch(void* const* d_in, const int* in_sizes, int n_in,
                              void* d_out, int out_size, void* d_ws, size_t ws_size,
                              hipStream_t stream) {
    const float* im    = (const float*)d_in[0];
    const float* tt    = (const float*)d_in[1];
    const float* rim   = (const float*)d_in[2];
    const float* rtt   = (const float*)d_in[3];
    const float* ru_im = (const float*)d_in[4];
    const float* ru_tt = (const float*)d_in[5];
    const float* l1_im = (const float*)d_in[6];
    const float* l1_tt = (const float*)d_in[7];
    const float* u_im  = (const float*)d_in[8];
    const float* u_tt  = (const float*)d_in[9];
    const float* lsc   = (const float*)d_in[10];
    const int*   offs  = (const int*)d_in[11];

    const int Bn = in_sizes[4];          // 4096
    const int D  = in_sizes[0] / Bn;     // 1024
    const int spm = Bn / 8;              // 8-row slabs per matrix

    char* base = (char*)d_ws;
    float* S_im = (float*)base;
    float* S_tt = S_im + Bn;
    float* diag = S_tt + Bn;
    float* red  = diag + Bn;             // [0]=pg, [1]=lg, [2]=ticket
    const size_t headBytes = (((size_t)(3 * Bn + 8) * sizeof(float)) + 255) & ~(size_t)255;
    const size_t matBytes  = (size_t)Bn * D;          // fp8: 1 B/elem
    unsigned char* buf0 = (unsigned char*)(base + headBytes);
    unsigned char* bRim = buf0;
    unsigned char* bTt  = buf0 + matBytes;
    unsigned char* bRtt = buf0 + 2 * matBytes;
    unsigned char* bIm  = buf0 + 3 * matBytes;

    prep_fp8<<<4 * spm + Bn / 4, 256, 0, stream>>>(
        im, tt, rim, rtt, bIm, bTt, bRim, bRtt, S_im, S_tt, diag, red, D, spm);

    dim3 ggrid(Bn / 128, Bn / 128, 2);
    gemm_expsum<<<ggrid, 256, 0, stream>>>(bRim, bTt, S_im, bRtt, bIm, S_tt,
                                           lsc, offs, Bn, D);

    final_kernel<<<8, 256, 0, stream>>>(S_im, S_tt, diag, ru_im, ru_tt,
                                        l1_im, l1_tt, u_im, u_tt, lsc,
                                        red, (float*)d_out, Bn);
}